// Round 11
// baseline (179.110 us; speedup 1.0000x reference)
//
#include <hip/hip_runtime.h>
#include <hip/hip_bf16.h>
#include <hip/hip_fp8.h>
#include <stdint.h>

// Shapes: b=2, n=5, k=5, q=75, t=196, c=384, s=k*t=980 (padded to 1024/class)
// M per b = 75*196 = 14700 (29 tiles of 512 rows). Outputs: logits[750] ++ cls_logits[750].
// Sim branch: fp8-e4m3 MX-scaled MFMA (scales=1.0); cls branch exact fp32.
// gemm: 512-thread blocks (8 waves, 64 A-rows each in 96 regs), B streamed once per
// block-half through double-buffered LDS, ONE barrier per 32-col chunk.
// Traffic model (calibrated r4-r10): dur ~= global_bytes/7.5 TB/s x ~1.5 stall factor.
// Tm=512 halves B duplication vs r10 (228 MB total) and gives 580 blocks ~ 2.27 rounds
// at 1 block/CU. Per-wave register shape identical to r10 (no spill at ~200 regs).

typedef __attribute__((ext_vector_type(8))) int int8v;      // f8f6f4 A/B operand (32 fp8)
typedef __attribute__((ext_vector_type(4))) float f32x4;    // MFMA C/D frag

__device__ __forceinline__ unsigned enc_f(float f) {
    unsigned b = __float_as_uint(f);
    return (b & 0x80000000u) ? ~b : (b | 0x80000000u);
}
__device__ __forceinline__ float dec_f(unsigned u) {
    unsigned b = (u & 0x80000000u) ? (u & 0x7FFFFFFFu) : ~u;
    return __uint_as_float(b);
}

__device__ __forceinline__ unsigned pack4_fp8(float a, float b, float c, float d) {
    int r = __builtin_amdgcn_cvt_pk_fp8_f32(a, b, 0, false);   // bytes 0,1
    r = __builtin_amdgcn_cvt_pk_fp8_f32(c, d, r, true);        // bytes 2,3
    return (unsigned)r;
}

// ---------------- fused prep: norm (16 lanes/row) | proto | init_P ----------------
__global__ void prep_kernel(const float* __restrict__ feat_query,
                            const float* __restrict__ feat_shot,
                            const float* __restrict__ x_shot,
                            unsigned* __restrict__ fqn,
                            unsigned* __restrict__ fsnp,
                            float* __restrict__ proto,
                            unsigned* __restrict__ P) {
    const int blk  = blockIdx.x;
    const int tid  = threadIdx.x;
    const int lane = tid & 63;
    const int wv   = tid >> 6;

    if (blk < 2478) {                       // ---- token L2 norm -> fp8, 4 rows/wave ----
        const int tr  = blk * 16 + wv * 4 + (lane >> 4);   // 0..39639
        const int l16 = lane & 15;
        if (tr >= 39640) return;

        const float* row;
        unsigned* o32;
        bool zero = false;
        if (tr < 29400) {
            row = feat_query + (size_t)tr * 384;
            o32 = fqn + (size_t)tr * 96;
        } else {
            const int sp = tr - 29400;          // padded shot row: [bn][1024]
            const int bn = sp >> 10;
            const int s  = sp & 1023;
            o32 = fsnp + (size_t)sp * 96;
            row = feat_shot + ((size_t)bn * 980 + s) * 384;
            zero = (s >= 980);
        }
        if (zero) {
#pragma unroll
            for (int j = 0; j < 6; ++j) o32[l16 + 16 * j] = 0u;
            return;
        }
        const float4* rf4 = (const float4*)row;
        float4 v[6];
        float ss = 0.f;
#pragma unroll
        for (int j = 0; j < 6; ++j) {
            v[j] = rf4[l16 + 16 * j];
            ss += v[j].x * v[j].x + v[j].y * v[j].y + v[j].z * v[j].z + v[j].w * v[j].w;
        }
#pragma unroll
        for (int off = 1; off < 16; off <<= 1) ss += __shfl_xor(ss, off, 64);
        const float sc = 1.0f / fmaxf(sqrtf(ss), 1e-8f);
#pragma unroll
        for (int j = 0; j < 6; ++j)
            o32[l16 + 16 * j] = pack4_fp8(v[j].x * sc, v[j].y * sc, v[j].z * sc, v[j].w * sc);
    } else if (blk < 2481) {                // ---- proto = l2norm(mean_k x_shot), fp32 ----
        const int gw = (blk - 2478) * 4 + wv;
        if (gw >= 10) return;
        const float* base = x_shot + (size_t)gw * 5 * 384;
        float v[6];
        float ss = 0.f;
#pragma unroll
        for (int j = 0; j < 6; ++j) {
            float s = 0.f;
#pragma unroll
            for (int kk = 0; kk < 5; ++kk) s += base[kk * 384 + lane + 64 * j];
            s *= 0.2f;
            v[j] = s;
            ss += s * s;
        }
#pragma unroll
        for (int off = 1; off < 64; off <<= 1) ss += __shfl_xor(ss, off, 64);
        const float scale = 1.0f / fmaxf(sqrtf(ss), 1e-12f);
#pragma unroll
        for (int j = 0; j < 6; ++j) proto[(size_t)gw * 384 + lane + 64 * j] = v[j] * scale;
    } else {                                // ---- init P to encoded -inf (0) ----
        const int i = (blk - 2481) * 256 + tid;
        if (i < 147000) P[i] = 0u;
    }
}

// ---------------- fp8 GEMM + row-max: 512 A-rows in regs (8 waves), B via dbuf LDS ----------------
// grid = 2b x 5cls x 2sh x 29mt = 580 blocks; 512 thr = 8 waves (64 rows each).
// B chunk = 32 cols x 384 B = 12 KB; 16 chunks per half-class; double-buffered (24 KB LDS).
// Loop: ds_write cur (prefetched last iter; vmcnt lands after a full compute phase)
// -> ONE barrier -> issue next prefetch -> compute (3 ks x [2 B-frags, 8 MFMA] per wave).
// Single-barrier safety: reads of a buffer and the next write to it are separated by
// exactly one barrier (write it uses buf[it&1], last read at compute it-2; barrier(it-1)
// sits between; concurrent compute it-1 reads the OTHER buffer).
// LDS layout: [col][24 granules of 16B], slot g' holds source granule
// (g'&~7)|((g'&7)^(col&7)); frag reads hit bank quadrant (2hi+c)^(l15&7) -> uniform.
__global__ __launch_bounds__(512, 2) void gemm_kernel(const uint8_t* __restrict__ fqn,
                                                      const uint8_t* __restrict__ fsnp,
                                                      unsigned* __restrict__ P) {
    __shared__ __align__(16) uint8_t Bl[2][12288];   // 24 KB double buffer

    const int bid = blockIdx.x;       // (((b*5+cls)*2)+sh)*29 + mt
    const int mt  = bid % 29;
    const int g1  = bid / 29;
    const int sh  = g1 & 1;
    const int bc  = g1 >> 1;          // b*5+cls
    const int b   = bc / 5;
    const int m0  = mt * 512;

    const int tid  = threadIdx.x;
    const int lane = tid & 63;
    const int wv   = tid >> 6;        // 0..7: wave's 64-row slice
    const int l15  = lane & 15;
    const int hi   = lane >> 4;

    const uint8_t* Ag = fqn  + (size_t)b * 14700 * 384;
    const uint8_t* Bg = fsnp + ((size_t)bc * 1024 + sh * 512) * 384;

    // ---- A fragments -> registers (one-time; wave wv holds rows m0+wv*64 .. +63) ----
    int8v A[4][3];
#pragma unroll
    for (int mi = 0; mi < 4; ++mi) {
        int row = m0 + wv * 64 + mi * 16 + l15;
        row = row < 14700 ? row : 14699;           // clamp; dead rows masked at epilogue
        const uint8_t* pa = Ag + (size_t)row * 384 + hi * 32;
#pragma unroll
        for (int ks = 0; ks < 3; ++ks) {
            const uint4 x = *(const uint4*)(pa + ks * 128);
            const uint4 y = *(const uint4*)(pa + ks * 128 + 16);
            A[mi][ks] = (int8v){(int)x.x, (int)x.y, (int)x.z, (int)x.w,
                                (int)y.x, (int)y.y, (int)y.z, (int)y.w};
        }
    }

    // ---- staging addresses: 768 granules of 16B per chunk over 512 threads ----
    // slot idx0 = tid (all), idx1 = 512 + tid (tid < 256 only)
    int src_off0, src_off1;
    {
        const int col0 = tid / 24, gp0 = tid - col0 * 24;
        const int g0 = (gp0 & ~7) | ((gp0 & 7) ^ (col0 & 7));
        src_off0 = col0 * 384 + g0 * 16;
        const int idx1 = 512 + tid;
        const int col1 = idx1 / 24, gp1 = idx1 - col1 * 24;
        const int g1s = (gp1 & ~7) | ((gp1 & 7) ^ (col1 & 7));
        src_off1 = col1 * 384 + g1s * 16;
    }
    const bool half = (tid < 256);

    // ---- prologue: prefetch chunk 0 into VGPRs ----
    uint4 nx0 = *(const uint4*)(Bg + src_off0);
    uint4 nx1 = half ? *(const uint4*)(Bg + src_off1) : make_uint4(0, 0, 0, 0);

    float rmax[4][4];
#pragma unroll
    for (int mi = 0; mi < 4; ++mi)
#pragma unroll
        for (int i = 0; i < 4; ++i) rmax[mi][i] = -3.0e38f;

    const int c0 = ((2 * hi + 0) ^ (l15 & 7)) * 16;
    const int c1 = ((2 * hi + 1) ^ (l15 & 7)) * 16;

    for (int it = 0; it < 16; ++it) {
        // write the chunk prefetched last iteration (vmcnt wait lands here, after a
        // full compute phase)
        uint8_t* wbuf = Bl[it & 1];
        *(uint4*)(&wbuf[tid * 16]) = nx0;
        if (half) *(uint4*)(&wbuf[(512 + tid) * 16]) = nx1;
        __syncthreads();

        // issue next chunk's prefetch (overlaps the compute below)
        if (it + 1 < 16) {
            const uint8_t* src = Bg + (size_t)(it + 1) * 32 * 384;
            nx0 = *(const uint4*)(src + src_off0);
            if (half) nx1 = *(const uint4*)(src + src_off1);
        }

        // compute on buffer it&1: every wave does all 32 cols x its 64 rows
        const uint8_t* buf = Bl[it & 1];
        f32x4 acc[4][2];
#pragma unroll
        for (int mi = 0; mi < 4; ++mi)
#pragma unroll
            for (int nf = 0; nf < 2; ++nf) acc[mi][nf] = (f32x4){0.f, 0.f, 0.f, 0.f};

#pragma unroll
        for (int ks = 0; ks < 3; ++ks) {
            int8v Bf[2];
#pragma unroll
            for (int nf = 0; nf < 2; ++nf) {
                const uint8_t* base = buf + (nf * 16 + l15) * 384 + ks * 128;
                const uint4 x = *(const uint4*)(base + c0);
                const uint4 y = *(const uint4*)(base + c1);
                Bf[nf] = (int8v){(int)x.x, (int)x.y, (int)x.z, (int)x.w,
                                 (int)y.x, (int)y.y, (int)y.z, (int)y.w};
            }
#pragma unroll
            for (int mi = 0; mi < 4; ++mi)
#pragma unroll
                for (int nf = 0; nf < 2; ++nf)
                    acc[mi][nf] = __builtin_amdgcn_mfma_scale_f32_16x16x128_f8f6f4(
                        A[mi][ks], Bf[nf], acc[mi][nf],
                        0, 0,                    // cbsz=fp8(e4m3), blgp=fp8(e4m3)
                        0, 0x7F7F7F7F,           // scale_a = 1.0
                        0, 0x7F7F7F7F);          // scale_b = 1.0
        }

        // fold row-max (mask padded cols >= 980)
#pragma unroll
        for (int nf = 0; nf < 2; ++nf) {
            if (sh * 512 + it * 32 + nf * 16 + l15 < 980) {
#pragma unroll
                for (int mi = 0; mi < 4; ++mi)
#pragma unroll
                    for (int i = 0; i < 4; ++i)
                        rmax[mi][i] = fmaxf(rmax[mi][i], acc[mi][nf][i]);
            }
        }
    }

    // ---- epilogue: max over the 16 col-lanes, then device-scope atomicMax ----
#pragma unroll
    for (int mi = 0; mi < 4; ++mi)
#pragma unroll
        for (int i = 0; i < 4; ++i) {
            float v = rmax[mi][i];
#pragma unroll
            for (int off = 1; off < 16; off <<= 1) v = fmaxf(v, __shfl_xor(v, off, 64));
            if (l15 == 0) {
                const int row = m0 + wv * 64 + mi * 16 + hi * 4 + i;
                if (row < 14700)
                    atomicMax(&P[(size_t)bc * 14700 + row], enc_f(v));
            }
        }
}

// ---------------- fused final: logits (mean over t of row maxima) | cls_logits ----------------
__global__ void final_kernel(const unsigned* __restrict__ P,
                             const float* __restrict__ xq,
                             const float* __restrict__ proto,
                             float* __restrict__ out) {
    const int blk  = blockIdx.x;
    const int tid  = threadIdx.x;
    const int lane = tid & 63;
    const int wv   = tid >> 6;

    if (blk < 188) {                        // ---- logits ----
        const int gw = blk * 4 + wv;        // (b*75+q)*5+n
        if (gw >= 750) return;
        const int n  = gw % 5;
        const int bq = gw / 5;
        const int b  = bq / 75;
        const int q  = bq % 75;
        const unsigned* row = P + (size_t)(b * 5 + n) * 14700 + q * 196;
        float s = 0.f;
        for (int t = lane; t < 196; t += 64) s += dec_f(row[t]);
#pragma unroll
        for (int off = 1; off < 64; off <<= 1) s += __shfl_xor(s, off, 64);
        if (lane == 0) out[gw] = s * (1.0f / 196.0f);
    } else {                                // ---- cls_logits ----
        const int gw = (blk - 188) * 4 + wv;   // b*75+q
        if (gw >= 150) return;
        const float* row = xq + (size_t)gw * 384;
        float u[6];
        float ss = 0.f;
#pragma unroll
        for (int j = 0; j < 6; ++j) { u[j] = row[lane + 64 * j]; ss += u[j] * u[j]; }
#pragma unroll
        for (int off = 1; off < 64; off <<= 1) ss += __shfl_xor(ss, off, 64);
        const float scale = 1.0f / fmaxf(sqrtf(ss), 1e-12f);
#pragma unroll
        for (int j = 0; j < 6; ++j) u[j] *= scale;
        const int b = gw / 75;
        for (int n = 0; n < 5; ++n) {
            const float* p = proto + (size_t)(b * 5 + n) * 384;
            float d = 0.f;
#pragma unroll
            for (int j = 0; j < 6; ++j) d += u[j] * p[lane + 64 * j];
#pragma unroll
            for (int off = 1; off < 64; off <<= 1) d += __shfl_xor(d, off, 64);
            if (lane == 0) out[750 + gw * 5 + n] = 10.0f * d;
        }
    }
}

extern "C" void kernel_launch(void* const* d_in, const int* in_sizes, int n_in,
                              void* d_out, int out_size, void* d_ws, size_t ws_size,
                              hipStream_t stream) {
    const float* feat_shot  = (const float*)d_in[0];  // [2,5,5,196,384]
    const float* feat_query = (const float*)d_in[1];  // [2,75,196,384]
    const float* x_shot     = (const float*)d_in[2];  // [2,5,5,384]
    const float* x_query    = (const float*)d_in[3];  // [2,75,384]
    float* out = (float*)d_out;
    char* ws = (char*)d_ws;

    // ws layout (15.8 MiB total)
    uint8_t*  fqn   = (uint8_t*)ws;                     // 29400*384  = 11,289,600 B (fp8)
    uint8_t*  fsnp  = (uint8_t*)(ws + 11289600);        // 10240*384  =  3,932,160 B (fp8)
    float*    proto = (float*)(ws + 15221760);          //      3,840 f32
    unsigned* P     = (unsigned*)(ws + 15237120);       //    147,000 u32

    prep_kernel<<<3056, 256, 0, stream>>>(feat_query, feat_shot, x_shot,
                                          (unsigned*)fqn, (unsigned*)fsnp, proto, P);
    gemm_kernel<<<580, 512, 0, stream>>>(fqn, fsnp, P);
    final_kernel<<<226, 256, 0, stream>>>(P, x_query, proto, out);
}